// Round 6
// baseline (4236.739 us; speedup 1.0000x reference)
//
#include <hip/hip_runtime.h>
#include <hip/hip_bf16.h>

#define F 128
#define ET 7
#define NT 32    // nodes per block in fused kernel
#define YS 132   // padded f32 row stride of y-tile
#define EG 4     // edges per half-wave per sweep

typedef __attribute__((ext_vector_type(8))) short short8;
typedef __attribute__((ext_vector_type(4))) float f32x4;
typedef __attribute__((ext_vector_type(4))) unsigned uint4v;

static __device__ __forceinline__ unsigned short f2bf(float f) {
    unsigned u = __builtin_bit_cast(unsigned, f);
    unsigned r = u + 0x7fffu + ((u >> 16) & 1u);   // RTNE
    return (unsigned short)(r >> 16);
}
static __device__ __forceinline__ float bf2f(unsigned short h) {
    unsigned u = ((unsigned)h) << 16;
    return __builtin_bit_cast(float, u);
}
static __device__ __forceinline__ float lo16(unsigned v) {
    return __builtin_bit_cast(float, v << 16);
}
static __device__ __forceinline__ float hi16(unsigned v) {
    return __builtin_bit_cast(float, v & 0xffff0000u);
}

// ---------------- W pre-pack into MFMA B-fragment order (verified r1) --------
__global__ __launch_bounds__(256) void prep_wfrag(const float* __restrict__ W,
                                                  unsigned short* __restrict__ Wfrag) {
    int tid = blockIdx.x * blockDim.x + threadIdx.x;
    if (tid >= ET * 2048) return;
    int i   = tid >> 11;
    int rem = tid & 2047;
    int c   = rem >> 8;
    int kk  = (rem >> 6) & 3;
    int l   = rem & 63;
    const float* Wi = W + (size_t)i * F * F;
    unsigned short* dst = Wfrag + (size_t)tid * 8;
    int o  = c * 16 + (l & 15);
    int kb = kk * 32 + 4 * (l >> 4);
#pragma unroll
    for (int e = 0; e < 8; ++e) {
        int k = kb + (e & 3) + 16 * (e >> 2);
        dst[e] = f2bf(Wi[k * F + o]);
    }
}

// ---------------- x -> bf16-packed, batch-interleaved: xb[n][b][64] dwords ---
__global__ __launch_bounds__(256) void xb_convert(const float* __restrict__ x,
                                                  unsigned* __restrict__ xb,
                                                  int N, long n_pairs) {
    long stride = (long)gridDim.x * blockDim.x;
    for (long t = (long)blockIdx.x * blockDim.x + threadIdx.x; t < n_pairs; t += stride) {
        long row = t >> 6;          // source row = b*N + n
        int  c   = (int)(t & 63);
        int  b   = row >= N;
        long n   = row - (long)b * N;
        float2 v = ((const float2*)x)[t];
        xb[(n << 7) + b * 64 + c] = (unsigned)f2bf(v.x) | ((unsigned)f2bf(v.y) << 16);
    }
}

// ---------------- CSR build -------------------------------------------------
__global__ __launch_bounds__(256) void hist_kernel(const int* __restrict__ startn,
                                                   int* __restrict__ counts,
                                                   int N, int E, int totE) {
    int tid = blockIdx.x * 256 + threadIdx.x;
    if (tid >= totE) return;
    int i = tid / E;
    atomicAdd(&counts[i * N + startn[tid]], 1);
}

__global__ __launch_bounds__(256) void block_sum(const int* __restrict__ counts,
                                                 int* __restrict__ partials, int CN) {
    int gid = blockIdx.x * 256 + threadIdx.x;
    int v = gid < CN ? counts[gid] : 0;
#pragma unroll
    for (int off = 1; off < 64; off <<= 1) v += __shfl_xor(v, off);
    __shared__ int sh[4];
    if ((threadIdx.x & 63) == 0) sh[threadIdx.x >> 6] = v;
    __syncthreads();
    if (threadIdx.x == 0) partials[blockIdx.x] = sh[0] + sh[1] + sh[2] + sh[3];
}

__global__ __launch_bounds__(256) void scan_partials(int* __restrict__ partials, int nblk) {
    __shared__ int sh[256];
    int carry = 0;
    for (int base = 0; base < nblk; base += 256) {
        int idx = base + threadIdx.x;
        int v = idx < nblk ? partials[idx] : 0;
        __syncthreads();
        sh[threadIdx.x] = v;
        __syncthreads();
        for (int o = 1; o < 256; o <<= 1) {
            int t = (int)threadIdx.x >= o ? sh[threadIdx.x - o] : 0;
            __syncthreads();
            sh[threadIdx.x] += t;
            __syncthreads();
        }
        int incl = sh[threadIdx.x];
        int total = sh[255];
        if (idx < nblk) partials[idx] = incl - v + carry;
        carry += total;
    }
}

__global__ __launch_bounds__(256) void scan_blocks(const int* __restrict__ counts,
                                                   const int* __restrict__ partials,
                                                   int* __restrict__ offsets,
                                                   int* __restrict__ cursor,
                                                   int CN, int totE) {
    __shared__ int sh[256];
    int gid = blockIdx.x * 256 + threadIdx.x;
    int v = gid < CN ? counts[gid] : 0;
    sh[threadIdx.x] = v;
    __syncthreads();
    for (int o = 1; o < 256; o <<= 1) {
        int t = (int)threadIdx.x >= o ? sh[threadIdx.x - o] : 0;
        __syncthreads();
        sh[threadIdx.x] += t;
        __syncthreads();
    }
    int excl = sh[threadIdx.x] - v + partials[blockIdx.x];
    if (gid < CN) { offsets[gid] = excl; cursor[gid] = excl; }
    if (gid == CN - 1) offsets[CN] = totE;
}

// payload.x = end_node | ((start_node & (NT-1)) << 20)   (end_node < 2^20)
__global__ __launch_bounds__(256) void fill_csr(const int* __restrict__ startn,
                                                const int* __restrict__ endn,
                                                const float* __restrict__ adj,
                                                int* __restrict__ cursor,
                                                int2* __restrict__ payload,
                                                int N, int E, int totE) {
    int tid = blockIdx.x * 256 + threadIdx.x;
    if (tid >= totE) return;
    int i = tid / E;
    int sn = startn[tid];
    int pos = atomicAdd(&cursor[i * N + sn], 1);
    int px = endn[tid] | ((sn & (NT - 1)) << 20);
    payload[pos] = make_int2(px, __builtin_bit_cast(int, adj[tid]));
}

// ---------------- fused aggregate-then-project -------------------------------
// Block = 512 thr (8 waves, 16 half-waves), owns NT=32 nodes (64 output rows).
// Per type i: zero f32 y-tile -> edge-parallel aggregation (half-wave per edge,
// one dwordx4 gather of the full 512B xb row, 8 ds_add_f32 into the node's
// y-row; EG-deep unroll keeps 64 gathers in flight per block) -> MFMA phase
// reads the f32 tile (row pad YS=132 => conflict-free b128), converts to bf16,
// accumulates into persistent acc. Epilogue adds sum_i(sadj_i*bias_i).
__global__ __launch_bounds__(512, 8) void fused_agg_gemm(
        const unsigned* __restrict__ xb,          // [N][2][64] dwords (bf16x2)
        const unsigned short* __restrict__ Wfrag, // [7][2048][8]
        const float* __restrict__ bias,           // [7][128]
        const int* __restrict__ offsets,          // [7N+1]
        const int2* __restrict__ payload,         // [7E]
        float* __restrict__ out, int N) {
    __shared__ float ylds[2 * NT * YS];           // 64 rows x 132 f32
    __shared__ float sadjl[ET][NT];

    int tid  = threadIdx.x;
    int wave = tid >> 6;
    int lane = tid & 63;
    int hw   = tid >> 5;           // half-wave id, 0..15
    int hl   = tid & 31;
    int lr   = lane & 15;
    int lg   = lane >> 4;
    int rt   = wave & 3;           // row-tile for MFMA
    int ct4  = (wave >> 2) * 4;    // col-tile base for MFMA
    int n0   = blockIdx.x * NT;

    int hb = hl >> 4;              // batch of this lane's 16B chunk
    int c0 = (hl & 15) * 8;        // f32 col base within row

    int zr = tid >> 3;             // zero phase: row 0..63
    int zc = (tid & 7) * 16;       // cols zc..zc+15

    f32x4 acc[4];
#pragma unroll
    for (int c = 0; c < 4; ++c) acc[c] = (f32x4){0.f, 0.f, 0.f, 0.f};

    for (int i = 0; i < ET; ++i) {
        // ---- zero y-tile (and sadj once) ----
#pragma unroll
        for (int u = 0; u < 4; ++u)
            *(f32x4*)&ylds[zr * YS + zc + u * 4] = (f32x4){0.f, 0.f, 0.f, 0.f};
        if (i == 0 && tid < ET * NT) ((float*)sadjl)[tid] = 0.f;
        __syncthreads();

        // ---- edge-parallel aggregation over contiguous CSR range ----
        int nEnd = (n0 + NT < N) ? n0 + NT : N;
        int beg = offsets[i * N + n0];
        int end = offsets[i * N + nEnd];

        for (int e0 = beg + hw * EG; e0 < end; e0 += 16 * EG) {
#pragma unroll
            for (int g = 0; g < EG; ++g) {
                int e = e0 + g;
                int2 p = (e < end) ? payload[e] : make_int2(0, 0);
                float w = __builtin_bit_cast(float, p.y);
                int en = p.x & 0xFFFFF;
                int nl = (p.x >> 20) & (NT - 1);
                uint4v v = *(const uint4v*)(xb + ((size_t)en << 7) + hl * 4);
                float* yr = &ylds[(hb * NT + nl) * YS + c0];
                atomicAdd(&yr[0], w * lo16(v[0]));
                atomicAdd(&yr[1], w * hi16(v[0]));
                atomicAdd(&yr[2], w * lo16(v[1]));
                atomicAdd(&yr[3], w * hi16(v[1]));
                atomicAdd(&yr[4], w * lo16(v[2]));
                atomicAdd(&yr[5], w * hi16(v[2]));
                atomicAdd(&yr[6], w * lo16(v[3]));
                atomicAdd(&yr[7], w * hi16(v[3]));
                if (hl == 0) atomicAdd(&sadjl[i][nl], w);
            }
        }
        __syncthreads();

        // ---- MFMA: wave -> rows rt*16..+15, col-tiles ct4..ct4+3 ----
        int r = rt * 16 + lr;
#pragma unroll
        for (int kk = 0; kk < 4; ++kk) {
            int k0 = kk * 32 + 4 * lg;
            f32x4 flo = *(const f32x4*)&ylds[r * YS + k0];
            f32x4 fhi = *(const f32x4*)&ylds[r * YS + k0 + 16];
            short8 afrag;
            afrag[0] = (short)f2bf(flo[0]);
            afrag[1] = (short)f2bf(flo[1]);
            afrag[2] = (short)f2bf(flo[2]);
            afrag[3] = (short)f2bf(flo[3]);
            afrag[4] = (short)f2bf(fhi[0]);
            afrag[5] = (short)f2bf(fhi[1]);
            afrag[6] = (short)f2bf(fhi[2]);
            afrag[7] = (short)f2bf(fhi[3]);
            const unsigned short* wbp = Wfrag + ((size_t)i * 2048 + (size_t)kk * 64 + lane) * 8;
#pragma unroll
            for (int c = 0; c < 4; ++c) {
                short8 bfrag = *(const short8*)(wbp + (size_t)(ct4 + c) * 2048);
                acc[c] = __builtin_amdgcn_mfma_f32_16x16x32_bf16(afrag, bfrag, acc[c], 0, 0, 0);
            }
        }
        __syncthreads();
    }

    // ---- epilogue: add sum(adj)*bias, store out once ----
#pragma unroll
    for (int c = 0; c < 4; ++c) {
        int col = (ct4 + c) * 16 + lr;
        float bv[ET];
#pragma unroll
        for (int i = 0; i < ET; ++i) bv[i] = bias[i * F + col];
#pragma unroll
        for (int j = 0; j < 4; ++j) {
            int row = rt * 16 + lg * 4 + j;
            int nl = row & (NT - 1);
            int b  = row >> 5;
            int n  = n0 + nl;
            float vv = acc[c][j];
#pragma unroll
            for (int i = 0; i < ET; ++i) vv += sadjl[i][nl] * bv[i];
            if (n < N) out[((size_t)(b * N + n)) * F + col] = vv;
        }
    }
}

// ---------------- fallbacks --------------------------------------------------
__global__ __launch_bounds__(256) void gemm_h(const float* __restrict__ x,
                                              const unsigned short* __restrict__ Wfrag,
                                              const float* __restrict__ bias,
                                              unsigned short* __restrict__ hb,
                                              int M) {
    int wave = threadIdx.x >> 6;
    int lane = threadIdx.x & 63;
    int row_base = blockIdx.x * 128 + wave * 32;
    int lr = lane & 15;
    int lg = lane >> 4;
    f32x4 acc[2][8];
#pragma unroll
    for (int t = 0; t < 2; ++t)
#pragma unroll
        for (int c = 0; c < 8; ++c)
            acc[t][c] = (f32x4){0.f, 0.f, 0.f, 0.f};
#pragma unroll
    for (int kk = 0; kk < 4; ++kk) {
        int k0 = kk * 32 + 4 * lg;
        short8 afrag[2];
#pragma unroll
        for (int t = 0; t < 2; ++t) {
            int r = row_base + t * 16 + lr;
            r = r < M ? r : M - 1;
            float4 v0 = *(const float4*)(x + (size_t)r * F + k0);
            float4 v1 = *(const float4*)(x + (size_t)r * F + k0 + 16);
            short8 a;
            a[0] = (short)f2bf(v0.x); a[1] = (short)f2bf(v0.y);
            a[2] = (short)f2bf(v0.z); a[3] = (short)f2bf(v0.w);
            a[4] = (short)f2bf(v1.x); a[5] = (short)f2bf(v1.y);
            a[6] = (short)f2bf(v1.z); a[7] = (short)f2bf(v1.w);
            afrag[t] = a;
        }
#pragma unroll
        for (int c = 0; c < 8; ++c) {
            short8 bfrag = *(const short8*)(Wfrag + (size_t)((c * 4 + kk) * 64 + lane) * 8);
            acc[0][c] = __builtin_amdgcn_mfma_f32_16x16x32_bf16(afrag[0], bfrag, acc[0][c], 0, 0, 0);
            acc[1][c] = __builtin_amdgcn_mfma_f32_16x16x32_bf16(afrag[1], bfrag, acc[1][c], 0, 0, 0);
        }
    }
#pragma unroll
    for (int c = 0; c < 8; ++c) {
        int o = c * 16 + lr;
        float bvv = bias[o];
#pragma unroll
        for (int t = 0; t < 2; ++t)
#pragma unroll
            for (int j = 0; j < 4; ++j) {
                int r = row_base + t * 16 + lg * 4 + j;
                if (r < M) hb[(size_t)r * F + o] = f2bf(acc[t][c][j] + bvv);
            }
    }
}

__global__ __launch_bounds__(256) void edge_scatter(const unsigned short* __restrict__ hb,
                                                    const float* __restrict__ adj,
                                                    const int* __restrict__ endn,
                                                    const int* __restrict__ startn,
                                                    float* __restrict__ out,
                                                    int N, int E) {
    int e = blockIdx.x;
    if (e >= E) return;
    int b = threadIdx.x >> 7;
    int f = threadIdx.x & 127;
    float a = adj[e];
    int en = endn[e];
    int sn = startn[e];
    float v = a * bf2f(hb[((size_t)(b * N + en)) * F + f]);
    unsafeAtomicAdd(&out[((size_t)(b * N + sn)) * F + f], v);
}

__global__ __launch_bounds__(256) void edge_fused_slow(const float* __restrict__ x,
                                                       const float* __restrict__ W,
                                                       const float* __restrict__ bias,
                                                       const float* __restrict__ adj,
                                                       const int* __restrict__ endn,
                                                       const int* __restrict__ startn,
                                                       float* __restrict__ out,
                                                       int N, int E) {
    __shared__ float xrow[2][F];
    int e = blockIdx.x;
    if (e >= E) return;
    int b = threadIdx.x >> 7;
    int f = threadIdx.x & 127;
    int en = endn[e], sn = startn[e];
    xrow[b][f] = x[((size_t)(b * N + en)) * F + f];
    __syncthreads();
    float acc = bias[f];
#pragma unroll 8
    for (int k = 0; k < F; ++k) acc += xrow[b][k] * W[k * F + f];
    unsafeAtomicAdd(&out[((size_t)(b * N + sn)) * F + f], adj[e] * acc);
}

// ---------------- launch -----------------------------------------------------
extern "C" void kernel_launch(void* const* d_in, const int* in_sizes, int n_in,
                              void* d_out, int out_size, void* d_ws, size_t ws_size,
                              hipStream_t stream) {
    const float* x      = (const float*)d_in[0];
    const float* W      = (const float*)d_in[1];
    const float* bias   = (const float*)d_in[2];
    const float* adj    = (const float*)d_in[3];
    const int*   endn   = (const int*)d_in[4];
    const int*   startn = (const int*)d_in[5];

    const int B = 2;
    const int N = in_sizes[0] / (B * F);  // 100000
    const int E = in_sizes[3] / ET;       // 400000
    const int M = B * N;                  // 200000
    const int totE = ET * E;              // 2.8M
    const int CN = ET * N;                // 700000
    const int nblk = (CN + 255) / 256;
    float* out = (float*)d_out;

    // ws layout (256B-aligned chunks)
    size_t off = 0;
    auto take = [&](size_t bytes) { size_t o = off; off = (off + bytes + 255) & ~(size_t)255; return o; };
    size_t o_wfrag    = take((size_t)ET * F * F * 2);
    size_t o_counts   = take((size_t)CN * 4);
    size_t o_offsets  = take((size_t)(CN + 1) * 4);
    size_t o_cursor   = take((size_t)CN * 4);
    size_t o_partials = take((size_t)nblk * 4);
    size_t o_payload  = take((size_t)totE * 8);
    size_t o_xb       = take((size_t)M * F * 2);
    size_t need_new = off;
    size_t need_old = 256 * 1024 + (size_t)M * F * 2;

    if (ws_size >= need_new) {
        char* ws = (char*)d_ws;
        unsigned short* Wfrag = (unsigned short*)(ws + o_wfrag);
        int*  counts   = (int*)(ws + o_counts);
        int*  offsets  = (int*)(ws + o_offsets);
        int*  cursor   = (int*)(ws + o_cursor);
        int*  partials = (int*)(ws + o_partials);
        int2* payload  = (int2*)(ws + o_payload);
        unsigned* xbuf = (unsigned*)(ws + o_xb);

        hipMemsetAsync(counts, 0, (size_t)CN * 4, stream);
        prep_wfrag<<<(ET * 2048 + 255) / 256, 256, 0, stream>>>(W, Wfrag);
        xb_convert<<<2048, 256, 0, stream>>>(x, xbuf, N, (long)M * (F / 2));
        hist_kernel<<<(totE + 255) / 256, 256, 0, stream>>>(startn, counts, N, E, totE);
        block_sum<<<nblk, 256, 0, stream>>>(counts, partials, CN);
        scan_partials<<<1, 256, 0, stream>>>(partials, nblk);
        scan_blocks<<<nblk, 256, 0, stream>>>(counts, partials, offsets, cursor, CN, totE);
        fill_csr<<<(totE + 255) / 256, 256, 0, stream>>>(startn, endn, adj, cursor, payload, N, E, totE);

        int fgrid = (N + NT - 1) / NT;   // 3125
        fused_agg_gemm<<<fgrid, 512, 0, stream>>>(xbuf, Wfrag, bias, offsets, payload, out, N);
    } else if (ws_size >= need_old) {
        hipMemsetAsync(out, 0, (size_t)out_size * sizeof(float), stream);
        unsigned short* Wfrag = (unsigned short*)d_ws;
        unsigned short* hbuf  = (unsigned short*)((char*)d_ws + 256 * 1024);
        prep_wfrag<<<(ET * 2048 + 255) / 256, 256, 0, stream>>>(W, Wfrag);
        int ggrid = (M + 127) / 128;
        for (int i = 0; i < ET; ++i) {
            gemm_h<<<ggrid, 256, 0, stream>>>(x, Wfrag + (size_t)i * F * F, bias + i * F, hbuf, M);
            edge_scatter<<<E, 256, 0, stream>>>(hbuf, adj + (size_t)i * E, endn + (size_t)i * E,
                                                startn + (size_t)i * E, out, N, E);
        }
    } else {
        hipMemsetAsync(out, 0, (size_t)out_size * sizeof(float), stream);
        for (int i = 0; i < ET; ++i) {
            edge_fused_slow<<<E, 256, 0, stream>>>(x, W + (size_t)i * F * F, bias + i * F,
                                                   adj + (size_t)i * E, endn + (size_t)i * E,
                                                   startn + (size_t)i * E, out, N, E);
        }
    }
}

// Round 7
// 803.704 us; speedup vs baseline: 5.2715x; 5.2715x over previous
//
#include <hip/hip_runtime.h>
#include <hip/hip_bf16.h>

#define F 128
#define ET 7
#define NT 32   // nodes per block in fused kernel

typedef __attribute__((ext_vector_type(8))) short short8;
typedef __attribute__((ext_vector_type(4))) float f32x4;
typedef __attribute__((ext_vector_type(4))) unsigned uint4v;

static __device__ __forceinline__ unsigned short f2bf(float f) {
    unsigned u = __builtin_bit_cast(unsigned, f);
    unsigned r = u + 0x7fffu + ((u >> 16) & 1u);   // RTNE
    return (unsigned short)(r >> 16);
}
static __device__ __forceinline__ float bf2f(unsigned short h) {
    unsigned u = ((unsigned)h) << 16;
    return __builtin_bit_cast(float, u);
}
static __device__ __forceinline__ float lo16(unsigned v) {
    return __builtin_bit_cast(float, v << 16);
}
static __device__ __forceinline__ float hi16(unsigned v) {
    return __builtin_bit_cast(float, v & 0xffff0000u);
}

// ---------------- W pre-pack into MFMA B-fragment order (verified r1) --------
__global__ __launch_bounds__(256) void prep_wfrag(const float* __restrict__ W,
                                                  unsigned short* __restrict__ Wfrag) {
    int tid = blockIdx.x * blockDim.x + threadIdx.x;
    if (tid >= ET * 2048) return;
    int i   = tid >> 11;
    int rem = tid & 2047;
    int c   = rem >> 8;
    int kk  = (rem >> 6) & 3;
    int l   = rem & 63;
    const float* Wi = W + (size_t)i * F * F;
    unsigned short* dst = Wfrag + (size_t)tid * 8;
    int o  = c * 16 + (l & 15);
    int kb = kk * 32 + 4 * (l >> 4);
#pragma unroll
    for (int e = 0; e < 8; ++e) {
        int k = kb + (e & 3) + 16 * (e >> 2);
        dst[e] = f2bf(Wi[k * F + o]);
    }
}

// ---------------- x -> bf16-packed, batch-interleaved: xb[n][b][64] dwords ---
__global__ __launch_bounds__(256) void xb_convert(const float* __restrict__ x,
                                                  unsigned* __restrict__ xb,
                                                  int N, long n_pairs) {
    long stride = (long)gridDim.x * blockDim.x;
    for (long t = (long)blockIdx.x * blockDim.x + threadIdx.x; t < n_pairs; t += stride) {
        long row = t >> 6;          // source row = b*N + n
        int  c   = (int)(t & 63);
        int  b   = row >= N;
        long n   = row - (long)b * N;
        float2 v = ((const float2*)x)[t];
        xb[(n << 7) + b * 64 + c] = (unsigned)f2bf(v.x) | ((unsigned)f2bf(v.y) << 16);
    }
}

// ---------------- CSR build (round-2 verified) -------------------------------
__global__ __launch_bounds__(256) void hist_kernel(const int* __restrict__ startn,
                                                   int* __restrict__ counts,
                                                   int N, int E, int totE) {
    int tid = blockIdx.x * 256 + threadIdx.x;
    if (tid >= totE) return;
    int i = tid / E;
    atomicAdd(&counts[i * N + startn[tid]], 1);
}

__global__ __launch_bounds__(256) void block_sum(const int* __restrict__ counts,
                                                 int* __restrict__ partials, int CN) {
    int gid = blockIdx.x * 256 + threadIdx.x;
    int v = gid < CN ? counts[gid] : 0;
#pragma unroll
    for (int off = 1; off < 64; off <<= 1) v += __shfl_xor(v, off);
    __shared__ int sh[4];
    if ((threadIdx.x & 63) == 0) sh[threadIdx.x >> 6] = v;
    __syncthreads();
    if (threadIdx.x == 0) partials[blockIdx.x] = sh[0] + sh[1] + sh[2] + sh[3];
}

__global__ __launch_bounds__(256) void scan_partials(int* __restrict__ partials, int nblk) {
    __shared__ int sh[256];
    int carry = 0;
    for (int base = 0; base < nblk; base += 256) {
        int idx = base + threadIdx.x;
        int v = idx < nblk ? partials[idx] : 0;
        __syncthreads();
        sh[threadIdx.x] = v;
        __syncthreads();
        for (int o = 1; o < 256; o <<= 1) {
            int t = (int)threadIdx.x >= o ? sh[threadIdx.x - o] : 0;
            __syncthreads();
            sh[threadIdx.x] += t;
            __syncthreads();
        }
        int incl = sh[threadIdx.x];
        int total = sh[255];
        if (idx < nblk) partials[idx] = incl - v + carry;
        carry += total;
    }
}

__global__ __launch_bounds__(256) void scan_blocks(const int* __restrict__ counts,
                                                   const int* __restrict__ partials,
                                                   int* __restrict__ offsets,
                                                   int* __restrict__ cursor,
                                                   int CN, int totE) {
    __shared__ int sh[256];
    int gid = blockIdx.x * 256 + threadIdx.x;
    int v = gid < CN ? counts[gid] : 0;
    sh[threadIdx.x] = v;
    __syncthreads();
    for (int o = 1; o < 256; o <<= 1) {
        int t = (int)threadIdx.x >= o ? sh[threadIdx.x - o] : 0;
        __syncthreads();
        sh[threadIdx.x] += t;
        __syncthreads();
    }
    int excl = sh[threadIdx.x] - v + partials[blockIdx.x];
    if (gid < CN) { offsets[gid] = excl; cursor[gid] = excl; }
    if (gid == CN - 1) offsets[CN] = totE;
}

// payload.x = end_node | ((start_node & (NT-1)) << 20)   (end_node < 2^20)
__global__ __launch_bounds__(256) void fill_csr(const int* __restrict__ startn,
                                                const int* __restrict__ endn,
                                                const float* __restrict__ adj,
                                                int* __restrict__ cursor,
                                                int2* __restrict__ payload,
                                                int N, int E, int totE) {
    int tid = blockIdx.x * 256 + threadIdx.x;
    if (tid >= totE) return;
    int i = tid / E;
    int sn = startn[tid];
    int pos = atomicAdd(&cursor[i * N + sn], 1);
    int px = endn[tid] | ((sn & (NT - 1)) << 20);
    payload[pos] = make_int2(px, __builtin_bit_cast(int, adj[tid]));
}

// ---------------- fused aggregate-then-project -------------------------------
// Block = 512 thr (8 waves), owns NT=32 nodes (64 output rows).
// Aggregation: WAVE-PER-NODE, static (wave w -> nodes w, w+8, w+16, w+24).
// Lane l owns dwords 2(l&31)..+1 of the node's 512B xb record (lanes 0-31:
// batch 0, 32-63: batch 1). Per edge: one uniform payload load + one dwordx2
// gather + 4 FMA per lane; 4-edge unrolled body keeps 4 independent gather
// chains in flight per wave; wave-uniform predicated tail. No ticket, no
// shuffles, no LDS atomics. Per-block CSR offsets preloaded into LDS.
// MFMA phase + epilogue identical to round-5 verified kernel.
__global__ __launch_bounds__(512, 4) void fused_agg_gemm(
        const unsigned* __restrict__ xb,          // [N][2][64] dwords (bf16x2)
        const unsigned short* __restrict__ Wfrag, // [7][2048][8]
        const float* __restrict__ bias,           // [7][128]
        const int* __restrict__ offsets,          // [7N+1]
        const int2* __restrict__ payload,         // [7E]
        float* __restrict__ out, int N) {
    __shared__ unsigned ylds[64 * 64];            // 64 rows x 64 dwords, swizzled
    __shared__ float sadjl[ET][NT];
    __shared__ int offs[ET][NT + 1];

    int tid  = threadIdx.x;
    int wave = tid >> 6;
    int lane = tid & 63;
    int hl   = lane & 31;
    int hb   = lane >> 5;          // batch this lane covers
    int lr   = lane & 15;
    int lg   = lane >> 4;
    int rt   = wave & 3;           // row-tile for MFMA
    int ct4  = (wave >> 2) * 4;    // col-tile base for MFMA
    int n0   = blockIdx.x * NT;

    // preload per-block CSR offsets (7 types x 33 entries)
    if (tid < ET * (NT + 1)) {
        int i = tid / (NT + 1);
        int j = tid - i * (NT + 1);
        int n = n0 + j;
        ((int*)offs)[tid] = offsets[i * N + (n < N ? n : N)];
    }

    f32x4 acc[4];
#pragma unroll
    for (int c = 0; c < 4; ++c) acc[c] = (f32x4){0.f, 0.f, 0.f, 0.f};

    __syncthreads();

    for (int i = 0; i < ET; ++i) {
        // ---- phase 1: aggregation, wave-per-node ----
#pragma unroll 1
        for (int q = 0; q < 4; ++q) {
            int nl  = wave + q * 8;
            int beg = offs[i][nl];
            int end = offs[i][nl + 1];
            float a0 = 0.f, a1 = 0.f, a2 = 0.f, a3 = 0.f, asum = 0.f;
            int k = beg;
            for (; k + 4 <= end; k += 4) {
                int2 p0 = payload[k];
                int2 p1 = payload[k + 1];
                int2 p2 = payload[k + 2];
                int2 p3 = payload[k + 3];
                uint2 v0 = *(const uint2*)(xb + ((size_t)(p0.x & 0xFFFFF) << 7) + (hb << 6) + (hl << 1));
                uint2 v1 = *(const uint2*)(xb + ((size_t)(p1.x & 0xFFFFF) << 7) + (hb << 6) + (hl << 1));
                uint2 v2 = *(const uint2*)(xb + ((size_t)(p2.x & 0xFFFFF) << 7) + (hb << 6) + (hl << 1));
                uint2 v3 = *(const uint2*)(xb + ((size_t)(p3.x & 0xFFFFF) << 7) + (hb << 6) + (hl << 1));
                float w0 = __builtin_bit_cast(float, p0.y);
                float w1 = __builtin_bit_cast(float, p1.y);
                float w2 = __builtin_bit_cast(float, p2.y);
                float w3 = __builtin_bit_cast(float, p3.y);
                asum += (w0 + w1) + (w2 + w3);
                a0 += w0 * lo16(v0.x) + w1 * lo16(v1.x) + w2 * lo16(v2.x) + w3 * lo16(v3.x);
                a1 += w0 * hi16(v0.x) + w1 * hi16(v1.x) + w2 * hi16(v2.x) + w3 * hi16(v3.x);
                a2 += w0 * lo16(v0.y) + w1 * lo16(v1.y) + w2 * lo16(v2.y) + w3 * lo16(v3.y);
                a3 += w0 * hi16(v0.y) + w1 * hi16(v1.y) + w2 * hi16(v2.y) + w3 * hi16(v3.y);
            }
            int rem = end - k;
            if (rem > 0) {
                int2 p = payload[k];
                uint2 v = *(const uint2*)(xb + ((size_t)(p.x & 0xFFFFF) << 7) + (hb << 6) + (hl << 1));
                float w = __builtin_bit_cast(float, p.y);
                asum += w;
                a0 += w * lo16(v.x); a1 += w * hi16(v.x);
                a2 += w * lo16(v.y); a3 += w * hi16(v.y);
            }
            if (rem > 1) {
                int2 p = payload[k + 1];
                uint2 v = *(const uint2*)(xb + ((size_t)(p.x & 0xFFFFF) << 7) + (hb << 6) + (hl << 1));
                float w = __builtin_bit_cast(float, p.y);
                asum += w;
                a0 += w * lo16(v.x); a1 += w * hi16(v.x);
                a2 += w * lo16(v.y); a3 += w * hi16(v.y);
            }
            if (rem > 2) {
                int2 p = payload[k + 2];
                uint2 v = *(const uint2*)(xb + ((size_t)(p.x & 0xFFFFF) << 7) + (hb << 6) + (hl << 1));
                float w = __builtin_bit_cast(float, p.y);
                asum += w;
                a0 += w * lo16(v.x); a1 += w * hi16(v.x);
                a2 += w * lo16(v.y); a3 += w * hi16(v.y);
            }
            // pack + store this node's y-row slice (lane-exclusive, no atomics)
            unsigned pk0 = (unsigned)f2bf(a0) | ((unsigned)f2bf(a1) << 16);
            unsigned pk1 = (unsigned)f2bf(a2) | ((unsigned)f2bf(a3) << 16);
            int r   = hb * NT + nl;
            int col = hl << 1;
            *(uint2*)&ylds[(r * 64 + col) ^ ((r & 7) << 2)] = make_uint2(pk0, pk1);
            if (lane == 0) sadjl[i][nl] = asum;
        }
        __syncthreads();
        // ---- phase 2: MFMA (round-5 verified path) ----
        int row = rt * 16 + lr;
        int s = (row & 7) << 2;
#pragma unroll
        for (int kk = 0; kk < 4; ++kk) {
            int d0 = (row * 64 + kk * 16 + lg * 2) ^ s;
            int d1 = (row * 64 + kk * 16 + lg * 2 + 8) ^ s;
            uint2 c0 = *(const uint2*)&ylds[d0];
            uint2 c1 = *(const uint2*)&ylds[d1];
            uint4v av = {c0.x, c0.y, c1.x, c1.y};
            short8 afrag = __builtin_bit_cast(short8, av);
            const unsigned short* wbp = Wfrag + ((size_t)i * 2048 + (size_t)kk * 64 + lane) * 8;
#pragma unroll
            for (int c = 0; c < 4; ++c) {
                short8 bfrag = *(const short8*)(wbp + (size_t)(ct4 + c) * 2048);
                acc[c] = __builtin_amdgcn_mfma_f32_16x16x32_bf16(afrag, bfrag, acc[c], 0, 0, 0);
            }
        }
        __syncthreads();
    }

    // ---- epilogue: add sum(adj)*bias, store out once ----
#pragma unroll
    for (int c = 0; c < 4; ++c) {
        int col = (ct4 + c) * 16 + lr;
        float bv[ET];
#pragma unroll
        for (int i = 0; i < ET; ++i) bv[i] = bias[i * F + col];
#pragma unroll
        for (int j = 0; j < 4; ++j) {
            int row = rt * 16 + lg * 4 + j;
            int nl = row & (NT - 1);
            int b  = row >> 5;
            int n  = n0 + nl;
            float vv = acc[c][j];
#pragma unroll
            for (int i = 0; i < ET; ++i) vv += sadjl[i][nl] * bv[i];
            if (n < N) out[((size_t)(b * N + n)) * F + col] = vv;
        }
    }
}

// ---------------- fallbacks --------------------------------------------------
__global__ __launch_bounds__(256) void gemm_h(const float* __restrict__ x,
                                              const unsigned short* __restrict__ Wfrag,
                                              const float* __restrict__ bias,
                                              unsigned short* __restrict__ hb,
                                              int M) {
    int wave = threadIdx.x >> 6;
    int lane = threadIdx.x & 63;
    int row_base = blockIdx.x * 128 + wave * 32;
    int lr = lane & 15;
    int lg = lane >> 4;
    f32x4 acc[2][8];
#pragma unroll
    for (int t = 0; t < 2; ++t)
#pragma unroll
        for (int c = 0; c < 8; ++c)
            acc[t][c] = (f32x4){0.f, 0.f, 0.f, 0.f};
#pragma unroll
    for (int kk = 0; kk < 4; ++kk) {
        int k0 = kk * 32 + 4 * lg;
        short8 afrag[2];
#pragma unroll
        for (int t = 0; t < 2; ++t) {
            int r = row_base + t * 16 + lr;
            r = r < M ? r : M - 1;
            float4 v0 = *(const float4*)(x + (size_t)r * F + k0);
            float4 v1 = *(const float4*)(x + (size_t)r * F + k0 + 16);
            short8 a;
            a[0] = (short)f2bf(v0.x); a[1] = (short)f2bf(v0.y);
            a[2] = (short)f2bf(v0.z); a[3] = (short)f2bf(v0.w);
            a[4] = (short)f2bf(v1.x); a[5] = (short)f2bf(v1.y);
            a[6] = (short)f2bf(v1.z); a[7] = (short)f2bf(v1.w);
            afrag[t] = a;
        }
#pragma unroll
        for (int c = 0; c < 8; ++c) {
            short8 bfrag = *(const short8*)(Wfrag + (size_t)((c * 4 + kk) * 64 + lane) * 8);
            acc[0][c] = __builtin_amdgcn_mfma_f32_16x16x32_bf16(afrag[0], bfrag, acc[0][c], 0, 0, 0);
            acc[1][c] = __builtin_amdgcn_mfma_f32_16x16x32_bf16(afrag[1], bfrag, acc[1][c], 0, 0, 0);
        }
    }
#pragma unroll
    for (int c = 0; c < 8; ++c) {
        int o = c * 16 + lr;
        float bvv = bias[o];
#pragma unroll
        for (int t = 0; t < 2; ++t)
#pragma unroll
            for (int j = 0; j < 4; ++j) {
                int r = row_base + t * 16 + lg * 4 + j;
                if (r < M) hb[(size_t)r * F + o] = f2bf(acc[t][c][j] + bvv);
            }
    }
}

__global__ __launch_bounds__(256) void edge_scatter(const unsigned short* __restrict__ hb,
                                                    const float* __restrict__ adj,
                                                    const int* __restrict__ endn,
                                                    const int* __restrict__ startn,
                                                    float* __restrict__ out,
                                                    int N, int E) {
    int e = blockIdx.x;
    if (e >= E) return;
    int b = threadIdx.x >> 7;
    int f = threadIdx.x & 127;
    float a = adj[e];
    int en = endn[e];
    int sn = startn[e];
    float v = a * bf2f(hb[((size_t)(b * N + en)) * F + f]);
    unsafeAtomicAdd(&out[((size_t)(b * N + sn)) * F + f], v);
}

__global__ __launch_bounds__(256) void edge_fused_slow(const float* __restrict__ x,
                                                       const float* __restrict__ W,
                                                       const float* __restrict__ bias,
                                                       const float* __restrict__ adj,
                                                       const int* __restrict__ endn,
                                                       const int* __restrict__ startn,
                                                       float* __restrict__ out,
                                                       int N, int E) {
    __shared__ float xrow[2][F];
    int e = blockIdx.x;
    if (e >= E) return;
    int b = threadIdx.x >> 7;
    int f = threadIdx.x & 127;
    int en = endn[e], sn = startn[e];
    xrow[b][f] = x[((size_t)(b * N + en)) * F + f];
    __syncthreads();
    float acc = bias[f];
#pragma unroll 8
    for (int k = 0; k < F; ++k) acc += xrow[b][k] * W[k * F + f];
    unsafeAtomicAdd(&out[((size_t)(b * N + sn)) * F + f], adj[e] * acc);
}

// ---------------- launch -----------------------------------------------------
extern "C" void kernel_launch(void* const* d_in, const int* in_sizes, int n_in,
                              void* d_out, int out_size, void* d_ws, size_t ws_size,
                              hipStream_t stream) {
    const float* x      = (const float*)d_in[0];
    const float* W      = (const float*)d_in[1];
    const float* bias   = (const float*)d_in[2];
    const float* adj    = (const float*)d_in[3];
    const int*   endn   = (const int*)d_in[4];
    const int*   startn = (const int*)d_in[5];

    const int B = 2;
    const int N = in_sizes[0] / (B * F);  // 100000
    const int E = in_sizes[3] / ET;       // 400000
    const int M = B * N;                  // 200000
    const int totE = ET * E;              // 2.8M
    const int CN = ET * N;                // 700000
    const int nblk = (CN + 255) / 256;
    float* out = (float*)d_out;

    // ws layout (256B-aligned chunks)
    size_t off = 0;
    auto take = [&](size_t bytes) { size_t o = off; off = (off + bytes + 255) & ~(size_t)255; return o; };
    size_t o_wfrag    = take((size_t)ET * F * F * 2);
    size_t o_counts   = take((size_t)CN * 4);
    size_t o_offsets  = take((size_t)(CN + 1) * 4);
    size_t o_cursor   = take((size_t)CN * 4);
    size_t o_partials = take((size_t)nblk * 4);
    size_t o_payload  = take((size_t)totE * 8);
    size_t o_xb       = take((size_t)M * F * 2);
    size_t need_new = off;
    size_t need_old = 256 * 1024 + (size_t)M * F * 2;

    if (ws_size >= need_new) {
        char* ws = (char*)d_ws;
        unsigned short* Wfrag = (unsigned short*)(ws + o_wfrag);
        int*  counts   = (int*)(ws + o_counts);
        int*  offsets  = (int*)(ws + o_offsets);
        int*  cursor   = (int*)(ws + o_cursor);
        int*  partials = (int*)(ws + o_partials);
        int2* payload  = (int2*)(ws + o_payload);
        unsigned* xbuf = (unsigned*)(ws + o_xb);

        hipMemsetAsync(counts, 0, (size_t)CN * 4, stream);
        prep_wfrag<<<(ET * 2048 + 255) / 256, 256, 0, stream>>>(W, Wfrag);
        xb_convert<<<2048, 256, 0, stream>>>(x, xbuf, N, (long)M * (F / 2));
        hist_kernel<<<(totE + 255) / 256, 256, 0, stream>>>(startn, counts, N, E, totE);
        block_sum<<<nblk, 256, 0, stream>>>(counts, partials, CN);
        scan_partials<<<1, 256, 0, stream>>>(partials, nblk);
        scan_blocks<<<nblk, 256, 0, stream>>>(counts, partials, offsets, cursor, CN, totE);
        fill_csr<<<(totE + 255) / 256, 256, 0, stream>>>(startn, endn, adj, cursor, payload, N, E, totE);

        int fgrid = (N + NT - 1) / NT;   // 3125
        fused_agg_gemm<<<fgrid, 512, 0, stream>>>(xbuf, Wfrag, bias, offsets, payload, out, N);
    } else if (ws_size >= need_old) {
        hipMemsetAsync(out, 0, (size_t)out_size * sizeof(float), stream);
        unsigned short* Wfrag = (unsigned short*)d_ws;
        unsigned short* hbuf  = (unsigned short*)((char*)d_ws + 256 * 1024);
        prep_wfrag<<<(ET * 2048 + 255) / 256, 256, 0, stream>>>(W, Wfrag);
        int ggrid = (M + 127) / 128;
        for (int i = 0; i < ET; ++i) {
            gemm_h<<<ggrid, 256, 0, stream>>>(x, Wfrag + (size_t)i * F * F, bias + i * F, hbuf, M);
            edge_scatter<<<E, 256, 0, stream>>>(hbuf, adj + (size_t)i * E, endn + (size_t)i * E,
                                                startn + (size_t)i * E, out, N, E);
        }
    } else {
        hipMemsetAsync(out, 0, (size_t)out_size * sizeof(float), stream);
        for (int i = 0; i < ET; ++i) {
            edge_fused_slow<<<E, 256, 0, stream>>>(x, W + (size_t)i * F * F, bias + i * F,
                                                   adj + (size_t)i * E, endn + (size_t)i * E,
                                                   startn + (size_t)i * E, out, N, E);
        }
    }
}

// Round 8
// 686.638 us; speedup vs baseline: 6.1703x; 1.1705x over previous
//
#include <hip/hip_runtime.h>
#include <hip/hip_bf16.h>

#define F 128
#define ET 7
#define NT 32   // nodes per block in fused kernel

typedef __attribute__((ext_vector_type(8))) short short8;
typedef __attribute__((ext_vector_type(4))) float f32x4;
typedef __attribute__((ext_vector_type(4))) unsigned uint4v;

static __device__ __forceinline__ unsigned f2bf(float f) {
    unsigned u = __builtin_bit_cast(unsigned, f);
    unsigned r = u + 0x7fffu + ((u >> 16) & 1u);   // RTNE
    return r >> 16;
}
static __device__ __forceinline__ float bf2f(unsigned short h) {
    unsigned u = ((unsigned)h) << 16;
    return __builtin_bit_cast(float, u);
}
static __device__ __forceinline__ float lo16(unsigned v) {
    return __builtin_bit_cast(float, v << 16);
}
static __device__ __forceinline__ float hi16(unsigned v) {
    return __builtin_bit_cast(float, v & 0xffff0000u);
}

// ---------------- W pre-pack into MFMA B-fragment order (verified r1) --------
__global__ __launch_bounds__(256) void prep_wfrag(const float* __restrict__ W,
                                                  unsigned short* __restrict__ Wfrag) {
    int tid = blockIdx.x * blockDim.x + threadIdx.x;
    if (tid >= ET * 2048) return;
    int i   = tid >> 11;
    int rem = tid & 2047;
    int c   = rem >> 8;
    int kk  = (rem >> 6) & 3;
    int l   = rem & 63;
    const float* Wi = W + (size_t)i * F * F;
    unsigned short* dst = Wfrag + (size_t)tid * 8;
    int o  = c * 16 + (l & 15);
    int kb = kk * 32 + 4 * (l >> 4);
#pragma unroll
    for (int e = 0; e < 8; ++e) {
        int k = kb + (e & 3) + 16 * (e >> 2);
        dst[e] = (unsigned short)f2bf(Wi[k * F + o]);
    }
}

// ---------------- x -> bf16-packed, batch-interleaved: xb[n][b][64] dwords ---
__global__ __launch_bounds__(256) void xb_convert(const float* __restrict__ x,
                                                  unsigned* __restrict__ xb,
                                                  int N, long n_pairs) {
    long stride = (long)gridDim.x * blockDim.x;
    for (long t = (long)blockIdx.x * blockDim.x + threadIdx.x; t < n_pairs; t += stride) {
        long row = t >> 6;          // source row = b*N + n
        int  c   = (int)(t & 63);
        int  b   = row >= N;
        long n   = row - (long)b * N;
        float2 v = ((const float2*)x)[t];
        xb[(n << 7) + b * 64 + c] = f2bf(v.x) | (f2bf(v.y) << 16);
    }
}

// ---------------- CSR build (round-2 verified) -------------------------------
__global__ __launch_bounds__(256) void hist_kernel(const int* __restrict__ startn,
                                                   int* __restrict__ counts,
                                                   int N, int E, int totE) {
    int tid = blockIdx.x * 256 + threadIdx.x;
    if (tid >= totE) return;
    int i = tid / E;
    atomicAdd(&counts[i * N + startn[tid]], 1);
}

__global__ __launch_bounds__(256) void block_sum(const int* __restrict__ counts,
                                                 int* __restrict__ partials, int CN) {
    int gid = blockIdx.x * 256 + threadIdx.x;
    int v = gid < CN ? counts[gid] : 0;
#pragma unroll
    for (int off = 1; off < 64; off <<= 1) v += __shfl_xor(v, off);
    __shared__ int sh[4];
    if ((threadIdx.x & 63) == 0) sh[threadIdx.x >> 6] = v;
    __syncthreads();
    if (threadIdx.x == 0) partials[blockIdx.x] = sh[0] + sh[1] + sh[2] + sh[3];
}

__global__ __launch_bounds__(256) void scan_partials(int* __restrict__ partials, int nblk) {
    __shared__ int sh[256];
    int carry = 0;
    for (int base = 0; base < nblk; base += 256) {
        int idx = base + threadIdx.x;
        int v = idx < nblk ? partials[idx] : 0;
        __syncthreads();
        sh[threadIdx.x] = v;
        __syncthreads();
        for (int o = 1; o < 256; o <<= 1) {
            int t = (int)threadIdx.x >= o ? sh[threadIdx.x - o] : 0;
            __syncthreads();
            sh[threadIdx.x] += t;
            __syncthreads();
        }
        int incl = sh[threadIdx.x];
        int total = sh[255];
        if (idx < nblk) partials[idx] = incl - v + carry;
        carry += total;
    }
}

__global__ __launch_bounds__(256) void scan_blocks(const int* __restrict__ counts,
                                                   const int* __restrict__ partials,
                                                   int* __restrict__ offsets,
                                                   int* __restrict__ cursor,
                                                   int CN, int totE) {
    __shared__ int sh[256];
    int gid = blockIdx.x * 256 + threadIdx.x;
    int v = gid < CN ? counts[gid] : 0;
    sh[threadIdx.x] = v;
    __syncthreads();
    for (int o = 1; o < 256; o <<= 1) {
        int t = (int)threadIdx.x >= o ? sh[threadIdx.x - o] : 0;
        __syncthreads();
        sh[threadIdx.x] += t;
        __syncthreads();
    }
    int excl = sh[threadIdx.x] - v + partials[blockIdx.x];
    if (gid < CN) { offsets[gid] = excl; cursor[gid] = excl; }
    if (gid == CN - 1) offsets[CN] = totE;
}

// payload.x = end_node | ((start_node & (NT-1)) << 20)   (end_node < 2^20)
__global__ __launch_bounds__(256) void fill_csr(const int* __restrict__ startn,
                                                const int* __restrict__ endn,
                                                const float* __restrict__ adj,
                                                int* __restrict__ cursor,
                                                int2* __restrict__ payload,
                                                int N, int E, int totE) {
    int tid = blockIdx.x * 256 + threadIdx.x;
    if (tid >= totE) return;
    int i = tid / E;
    int sn = startn[tid];
    int pos = atomicAdd(&cursor[i * N + sn], 1);
    int px = endn[tid] | ((sn & (NT - 1)) << 20);
    payload[pos] = make_int2(px, __builtin_bit_cast(int, adj[tid]));
}

// ---------------- fused aggregate-then-project -------------------------------
// Block = 512 thr (8 waves), owns NT=32 nodes (64 output rows).
// Phase 1 (NEW): per type, each wave takes a contiguous EDGE range snapped to
// node boundaries (degree-balanced; found via lane-parallel ballot over the 33
// LDS-cached offsets). Edges stream flat, 8-deep unrolled (8 payload loads +
// 8 uint2 gathers in flight); node id from payload bits 20-24; accumulator
// flushes to LDS on (wave-uniform) node change — nodes are wave-exclusive, so
// plain stores, no atomics. Degree-0 nodes zero-filled.
// Phase 2 MFMA + epilogue identical to round-5/7 verified path.
__global__ __launch_bounds__(512, 4) void fused_agg_gemm(
        const unsigned* __restrict__ xb,          // [N][2][64] dwords (bf16x2)
        const unsigned short* __restrict__ Wfrag, // [7][2048][8]
        const float* __restrict__ bias,           // [7][128]
        const int* __restrict__ offsets,          // [7N+1]
        const int2* __restrict__ payload,         // [7E]
        float* __restrict__ out, int N) {
    __shared__ unsigned ylds[64 * 64];            // 64 rows x 64 dwords, swizzled
    __shared__ float sadjl[ET][NT];
    __shared__ int offs[ET][NT + 1];

    int tid  = threadIdx.x;
    int wave = tid >> 6;
    int lane = tid & 63;
    int hl   = lane & 31;
    int hb   = lane >> 5;          // batch this lane covers
    int lr   = lane & 15;
    int lg   = lane >> 4;
    int rt   = wave & 3;           // row-tile for MFMA
    int ct4  = (wave >> 2) * 4;    // col-tile base for MFMA
    int n0   = blockIdx.x * NT;

    // preload per-block CSR offsets (7 types x 33 entries)
    if (tid < ET * (NT + 1)) {
        int i = tid / (NT + 1);
        int j = tid - i * (NT + 1);
        int n = n0 + j;
        ((int*)offs)[tid] = offsets[i * N + (n < N ? n : N)];
    }

    f32x4 acc[4];
#pragma unroll
    for (int c = 0; c < 4; ++c) acc[c] = (f32x4){0.f, 0.f, 0.f, 0.f};

    __syncthreads();

    const unsigned laneoff = (hb << 6) + (hl << 1);   // dword offset in 512B record
    const int colw = hl << 1;                         // this lane's y-row dword col

    for (int i = 0; i < ET; ++i) {
        // ---- degree-balanced node-aligned wave partition ----
        int base = offs[i][0];
        int tot  = offs[i][NT] - base;
        int tgt_s = base + (int)(((long)tot * wave) >> 3);
        int tgt_e = base + (int)(((long)tot * (wave + 1)) >> 3);
        int oj = (lane <= NT) ? offs[i][lane] : 0x7fffffff;
        unsigned long long ms = __ballot(oj >= tgt_s);
        unsigned long long me = __ballot(oj >= tgt_e);
        int js = __ffsll(ms) - 1;
        int je = (wave == 7) ? NT : (__ffsll(me) - 1);
        int kb = offs[i][js];
        int ke = offs[i][je];

        // ---- flat edge stream, 8-deep ----
        int cur = -1;
        float a0 = 0.f, a1 = 0.f, a2 = 0.f, a3 = 0.f, asum = 0.f;
        for (int k = kb; k < ke; k += 8) {
            int2 p[8];
            uint2 v[8];
#pragma unroll
            for (int j = 0; j < 8; ++j) {
                int idx = (k + j < ke) ? k + j : ke - 1;
                p[j] = payload[idx];
            }
#pragma unroll
            for (int j = 0; j < 8; ++j) {
                v[j] = *(const uint2*)(xb + (((size_t)(p[j].x & 0xFFFFF)) << 7) + laneoff);
            }
#pragma unroll
            for (int j = 0; j < 8; ++j) {
                bool ok = (k + j) < ke;
                float w = ok ? __builtin_bit_cast(float, p[j].y) : 0.f;
                int nl = (p[j].x >> 20) & (NT - 1);
                if (ok && nl != cur) {
                    if (cur >= 0) {
                        unsigned pk0 = f2bf(a0) | (f2bf(a1) << 16);
                        unsigned pk1 = f2bf(a2) | (f2bf(a3) << 16);
                        int r = hb * NT + cur;
                        *(uint2*)&ylds[(r * 64 + colw) ^ ((r & 7) << 2)] = make_uint2(pk0, pk1);
                        if (lane == 0) sadjl[i][cur] = asum;
                    }
                    cur = nl;
                    a0 = a1 = a2 = a3 = asum = 0.f;
                }
                asum += w;
                a0 += w * lo16(v[j].x); a1 += w * hi16(v[j].x);
                a2 += w * lo16(v[j].y); a3 += w * hi16(v[j].y);
            }
        }
        if (cur >= 0) {
            unsigned pk0 = f2bf(a0) | (f2bf(a1) << 16);
            unsigned pk1 = f2bf(a2) | (f2bf(a3) << 16);
            int r = hb * NT + cur;
            *(uint2*)&ylds[(r * 64 + colw) ^ ((r & 7) << 2)] = make_uint2(pk0, pk1);
            if (lane == 0) sadjl[i][cur] = asum;
        }
        // ---- zero-fill degree-0 nodes in [js, je) ----
        for (int j = js; j < je; ++j) {
            if (offs[i][j + 1] == offs[i][j]) {
                int r = hb * NT + j;
                *(uint2*)&ylds[(r * 64 + colw) ^ ((r & 7) << 2)] = make_uint2(0u, 0u);
                if (lane == 0) sadjl[i][j] = 0.f;
            }
        }
        __syncthreads();

        // ---- phase 2: MFMA (verified path) ----
        int row = rt * 16 + lr;
        int s = (row & 7) << 2;
#pragma unroll
        for (int kk = 0; kk < 4; ++kk) {
            int d0 = (row * 64 + kk * 16 + lg * 2) ^ s;
            int d1 = (row * 64 + kk * 16 + lg * 2 + 8) ^ s;
            uint2 c0 = *(const uint2*)&ylds[d0];
            uint2 c1 = *(const uint2*)&ylds[d1];
            uint4v av = {c0.x, c0.y, c1.x, c1.y};
            short8 afrag = __builtin_bit_cast(short8, av);
            const unsigned short* wbp = Wfrag + ((size_t)i * 2048 + (size_t)kk * 64 + lane) * 8;
#pragma unroll
            for (int c = 0; c < 4; ++c) {
                short8 bfrag = *(const short8*)(wbp + (size_t)(ct4 + c) * 2048);
                acc[c] = __builtin_amdgcn_mfma_f32_16x16x32_bf16(afrag, bfrag, acc[c], 0, 0, 0);
            }
        }
        __syncthreads();
    }

    // ---- epilogue: add sum(adj)*bias, store out once ----
#pragma unroll
    for (int c = 0; c < 4; ++c) {
        int col = (ct4 + c) * 16 + lr;
        float bv[ET];
#pragma unroll
        for (int i = 0; i < ET; ++i) bv[i] = bias[i * F + col];
#pragma unroll
        for (int j = 0; j < 4; ++j) {
            int row = rt * 16 + lg * 4 + j;
            int nl = row & (NT - 1);
            int b  = row >> 5;
            int n  = n0 + nl;
            float vv = acc[c][j];
#pragma unroll
            for (int i = 0; i < ET; ++i) vv += sadjl[i][nl] * bv[i];
            if (n < N) out[((size_t)(b * N + n)) * F + col] = vv;
        }
    }
}

// ---------------- fallbacks --------------------------------------------------
__global__ __launch_bounds__(256) void gemm_h(const float* __restrict__ x,
                                              const unsigned short* __restrict__ Wfrag,
                                              const float* __restrict__ bias,
                                              unsigned short* __restrict__ hb,
                                              int M) {
    int wave = threadIdx.x >> 6;
    int lane = threadIdx.x & 63;
    int row_base = blockIdx.x * 128 + wave * 32;
    int lr = lane & 15;
    int lg = lane >> 4;
    f32x4 acc[2][8];
#pragma unroll
    for (int t = 0; t < 2; ++t)
#pragma unroll
        for (int c = 0; c < 8; ++c)
            acc[t][c] = (f32x4){0.f, 0.f, 0.f, 0.f};
#pragma unroll
    for (int kk = 0; kk < 4; ++kk) {
        int k0 = kk * 32 + 4 * lg;
        short8 afrag[2];
#pragma unroll
        for (int t = 0; t < 2; ++t) {
            int r = row_base + t * 16 + lr;
            r = r < M ? r : M - 1;
            float4 v0 = *(const float4*)(x + (size_t)r * F + k0);
            float4 v1 = *(const float4*)(x + (size_t)r * F + k0 + 16);
            short8 a;
            a[0] = (short)f2bf(v0.x); a[1] = (short)f2bf(v0.y);
            a[2] = (short)f2bf(v0.z); a[3] = (short)f2bf(v0.w);
            a[4] = (short)f2bf(v1.x); a[5] = (short)f2bf(v1.y);
            a[6] = (short)f2bf(v1.z); a[7] = (short)f2bf(v1.w);
            afrag[t] = a;
        }
#pragma unroll
        for (int c = 0; c < 8; ++c) {
            short8 bfrag = *(const short8*)(Wfrag + (size_t)((c * 4 + kk) * 64 + lane) * 8);
            acc[0][c] = __builtin_amdgcn_mfma_f32_16x16x32_bf16(afrag[0], bfrag, acc[0][c], 0, 0, 0);
            acc[1][c] = __builtin_amdgcn_mfma_f32_16x16x32_bf16(afrag[1], bfrag, acc[1][c], 0, 0, 0);
        }
    }
#pragma unroll
    for (int c = 0; c < 8; ++c) {
        int o = c * 16 + lr;
        float bvv = bias[o];
#pragma unroll
        for (int t = 0; t < 2; ++t)
#pragma unroll
            for (int j = 0; j < 4; ++j) {
                int r = row_base + t * 16 + lg * 4 + j;
                if (r < M) hb[(size_t)r * F + o] = (unsigned short)f2bf(acc[t][c][j] + bvv);
            }
    }
}

__global__ __launch_bounds__(256) void edge_scatter(const unsigned short* __restrict__ hb,
                                                    const float* __restrict__ adj,
                                                    const int* __restrict__ endn,
                                                    const int* __restrict__ startn,
                                                    float* __restrict__ out,
                                                    int N, int E) {
    int e = blockIdx.x;
    if (e >= E) return;
    int b = threadIdx.x >> 7;
    int f = threadIdx.x & 127;
    float a = adj[e];
    int en = endn[e];
    int sn = startn[e];
    float v = a * bf2f(hb[((size_t)(b * N + en)) * F + f]);
    unsafeAtomicAdd(&out[((size_t)(b * N + sn)) * F + f], v);
}

__global__ __launch_bounds__(256) void edge_fused_slow(const float* __restrict__ x,
                                                       const float* __restrict__ W,
                                                       const float* __restrict__ bias,
                                                       const float* __restrict__ adj,
                                                       const int* __restrict__ endn,
                                                       const int* __restrict__ startn,
                                                       float* __restrict__ out,
                                                       int N, int E) {
    __shared__ float xrow[2][F];
    int e = blockIdx.x;
    if (e >= E) return;
    int b = threadIdx.x >> 7;
    int f = threadIdx.x & 127;
    int en = endn[e], sn = startn[e];
    xrow[b][f] = x[((size_t)(b * N + en)) * F + f];
    __syncthreads();
    float acc = bias[f];
#pragma unroll 8
    for (int k = 0; k < F; ++k) acc += xrow[b][k] * W[k * F + f];
    unsafeAtomicAdd(&out[((size_t)(b * N + sn)) * F + f], adj[e] * acc);
}

// ---------------- launch -----------------------------------------------------
extern "C" void kernel_launch(void* const* d_in, const int* in_sizes, int n_in,
                              void* d_out, int out_size, void* d_ws, size_t ws_size,
                              hipStream_t stream) {
    const float* x      = (const float*)d_in[0];
    const float* W      = (const float*)d_in[1];
    const float* bias   = (const float*)d_in[2];
    const float* adj    = (const float*)d_in[3];
    const int*   endn   = (const int*)d_in[4];
    const int*   startn = (const int*)d_in[5];

    const int B = 2;
    const int N = in_sizes[0] / (B * F);  // 100000
    const int E = in_sizes[3] / ET;       // 400000
    const int M = B * N;                  // 200000
    const int totE = ET * E;              // 2.8M
    const int CN = ET * N;                // 700000
    const int nblk = (CN + 255) / 256;
    float* out = (float*)d_out;

    // ws layout (256B-aligned chunks)
    size_t off = 0;
    auto take = [&](size_t bytes) { size_t o = off; off = (off + bytes + 255) & ~(size_t)255; return o; };
    size_t o_wfrag    = take((size_t)ET * F * F * 2);
    size_t o_counts   = take((size_t)CN * 4);
    size_t o_offsets  = take((size_t)(CN + 1) * 4);
    size_t o_cursor   = take((size_t)CN * 4);
    size_t o_partials = take((size_t)nblk * 4);
    size_t o_payload  = take((size_t)totE * 8);
    size_t o_xb       = take((size_t)M * F * 2);
    size_t need_new = off;
    size_t need_old = 256 * 1024 + (size_t)M * F * 2;

    if (ws_size >= need_new) {
        char* ws = (char*)d_ws;
        unsigned short* Wfrag = (unsigned short*)(ws + o_wfrag);
        int*  counts   = (int*)(ws + o_counts);
        int*  offsets  = (int*)(ws + o_offsets);
        int*  cursor   = (int*)(ws + o_cursor);
        int*  partials = (int*)(ws + o_partials);
        int2* payload  = (int2*)(ws + o_payload);
        unsigned* xbuf = (unsigned*)(ws + o_xb);

        hipMemsetAsync(counts, 0, (size_t)CN * 4, stream);
        prep_wfrag<<<(ET * 2048 + 255) / 256, 256, 0, stream>>>(W, Wfrag);
        xb_convert<<<2048, 256, 0, stream>>>(x, xbuf, N, (long)M * (F / 2));
        hist_kernel<<<(totE + 255) / 256, 256, 0, stream>>>(startn, counts, N, E, totE);
        block_sum<<<nblk, 256, 0, stream>>>(counts, partials, CN);
        scan_partials<<<1, 256, 0, stream>>>(partials, nblk);
        scan_blocks<<<nblk, 256, 0, stream>>>(counts, partials, offsets, cursor, CN, totE);
        fill_csr<<<(totE + 255) / 256, 256, 0, stream>>>(startn, endn, adj, cursor, payload, N, E, totE);

        int fgrid = (N + NT - 1) / NT;   // 3125
        fused_agg_gemm<<<fgrid, 512, 0, stream>>>(xbuf, Wfrag, bias, offsets, payload, out, N);
    } else if (ws_size >= need_old) {
        hipMemsetAsync(out, 0, (size_t)out_size * sizeof(float), stream);
        unsigned short* Wfrag = (unsigned short*)d_ws;
        unsigned short* hbuf  = (unsigned short*)((char*)d_ws + 256 * 1024);
        prep_wfrag<<<(ET * 2048 + 255) / 256, 256, 0, stream>>>(W, Wfrag);
        int ggrid = (M + 127) / 128;
        for (int i = 0; i < ET; ++i) {
            gemm_h<<<ggrid, 256, 0, stream>>>(x, Wfrag + (size_t)i * F * F, bias + i * F, hbuf, M);
            edge_scatter<<<E, 256, 0, stream>>>(hbuf, adj + (size_t)i * E, endn + (size_t)i * E,
                                                startn + (size_t)i * E, out, N, E);
        }
    } else {
        hipMemsetAsync(out, 0, (size_t)out_size * sizeof(float), stream);
        for (int i = 0; i < ET; ++i) {
            edge_fused_slow<<<E, 256, 0, stream>>>(x, W + (size_t)i * F * F, bias + i * F,
                                                   adj + (size_t)i * E, endn + (size_t)i * E,
                                                   startn + (size_t)i * E, out, N, E);
        }
    }
}